// Round 9
// baseline (230.713 us; speedup 1.0000x reference)
//
#include <hip/hip_runtime.h>

#define NN   10000
#define EE   160000
#define CINC 32
#define COUTC 32
#define RRR  6
#define MMM  3
#define RM   (RRR*MMM)      // 18
#define KK   (RM*CINC)      // 576
#define NPB  4              // nodes per block in k_conv
#define CE   8              // edges staged per node per chunk
#define CAP  64             // fixed bucket capacity per node (mean degree 16)
#define PART_STRIDE 132     // 4*32 + 4 pad (float2 units) per chunk
#define EPSV 1e-8f

// ---------------- build: phased weights + direct bucket scatter ----------------
// cursor[] pre-zeroed by hipMemsetAsync. Edges go straight into fixed-capacity
// per-node buckets; cursor[n] ends as the node's degree.

__global__ void __launch_bounds__(256)
k_build(const int* __restrict__ edges, int* __restrict__ cursor,
        const float* __restrict__ w1, const float* __restrict__ off1,
        const float* __restrict__ w2, const float* __restrict__ off2,
        float2* __restrict__ Wc1, float2* __restrict__ Wc2,
        int* __restrict__ srcs, int* __restrict__ eids)
{
    int i = blockIdx.x*blockDim.x + threadIdx.x;
    if (i < KK*COUTC) {
        int d = i % COUTC;
        int c = (i / COUTC) % CINC;
        float o1 = off1[c*COUTC + d];
        float o2 = off2[c*COUTC + d];
        float s1 = sinf(o1), c1 = cosf(o1);
        float s2 = sinf(o2), c2 = cosf(o2);
        Wc1[i] = make_float2(w1[i]*c1, w1[i]*s1);
        Wc2[i] = make_float2(w2[i]*c2, w2[i]*s2);
    }
    if (i < EE) {
        int src = edges[2*i];
        int tgt = edges[2*i+1];
        int pos = atomicAdd(&cursor[tgt], 1);
        if (pos < CAP) {                    // safety clamp (never hit in practice)
            srcs[tgt*CAP + pos] = src;
            eids[tgt*CAP + pos] = i;
        }
    }
}

// ---------------- degree counting-sort (single block) ----------------
// order[] = node ids sorted ascending by degree. Conv blocks then take 4
// consecutive ranks -> near-equal degrees within a block, so no wave idles
// at the __syncthreads behind a high-degree sibling.

__global__ void __launch_bounds__(1024)
k_order(const int* __restrict__ cnts, int* __restrict__ order) {
    __shared__ int bins[CAP+1];
    __shared__ int base[CAP+1];
    int t = threadIdx.x;
    if (t <= CAP) bins[t] = 0;
    __syncthreads();
    for (int n = t; n < NN; n += 1024) {
        int d = cnts[n]; if (d > CAP) d = CAP;
        atomicAdd(&bins[d], 1);
    }
    __syncthreads();
    if (t == 0) {
        int run = 0;
        #pragma unroll
        for (int b = 0; b <= CAP; ++b) { base[b] = run; run += bins[b]; }
    }
    __syncthreads();
    for (int n = t; n < NN; n += 1024) {
        int d = cnts[n]; if (d > CAP) d = CAP;
        int r = atomicAdd(&base[d], 1);
        order[r] = n;
    }
}

// ---------------- fused conv (+optional residual) + tangent nonlin ----------------
// 4 nodes/block (degree-sorted consecutive ranks), 1 wave per node. Edge phase
// chunked (CE=8): wave cooperatively stages the chunk's stencil rows into LDS
// (eid-indirect, zero VGPR buffering), then computes from LDS broadcast
// ds_read_b128; x rows direct (src via shfl, prefetched one pair ahead).
// Einsum: lane owns a d-pair; agg read as b128 q-pairs.

template<bool FINAL>
__global__ void __launch_bounds__(256)
k_conv(const float2* __restrict__ xin,      // (NN,32) complex input
       const int*  __restrict__ cnts,       // (NN) per-node edge count
       const int*  __restrict__ order,      // (NN) degree-sorted node ids
       const int*  __restrict__ srcs,       // (NN*CAP) src node buckets
       const int*  __restrict__ eids,       // (NN*CAP) edge id buckets
       const float4* __restrict__ stenc4,   // (EE,9) float4 = (EE,18) complex
       const float2* __restrict__ Wc,       // (KK,32) complex
       const float* __restrict__ bias,      // (32)
       const float2* __restrict__ xres,     // (NN,32) original xc (FINAL)
       const float2* __restrict__ resw,     // (32,32) complex (FINAL)
       float2* __restrict__ out)            // (NN,32) complex
{
    __shared__ __align__(16) float2 smem[NPB*KK];  // 18432 B; agg then part
    __shared__ float4 sten[NPB*CE*9];              // 4608 B stencil stage
    __shared__ int nid[NPB];
    float2* agg = smem;
    int t = threadIdx.x;

    if (t < NPB) nid[t] = order[blockIdx.x*NPB + t];
    __syncthreads();

    // ---- edge aggregation ----
    {
        int g = t >> 6;                     // node slot 0..3 (one wave each)
        int l = t & 63;
        int n = nid[g];
        int c = l & 31;
        int h = l >> 5;                     // half: alternate edges
        float4* myst = sten + g*(CE*9);
        float2 acc[RM];
        #pragma unroll
        for (int k = 0; k < RM; ++k) acc[k] = make_float2(0.f, 0.f);

        int beg = n*CAP;
        int cnt = cnts[n]; if (cnt > CAP) cnt = CAP;
        int end = beg + cnt;
        for (int eb = beg; eb < end; eb += CE) {
            int ne = end - eb; if (ne > CE) ne = CE;
            int nf4 = ne * 9;
            // stage stencil rows for this chunk (cooperative across the wave)
            for (int idx = l; idx < nf4; idx += 64) {
                int e = idx / 9;
                int comp = idx - e*9;
                int eid = eids[eb + e];
                myst[idx] = stenc4[(size_t)eid*9 + comp];
            }
            int srcv = 0;
            if (l < ne) srcv = srcs[eb + l];

            int le = h;
            float2 xA = make_float2(0.f, 0.f);
            if (le < ne) {
                int s0 = __shfl(srcv, le, 64);
                xA = xin[(size_t)s0 * CINC + c];
            }
            int iters = (ne + 1) >> 1;
            for (int i = 0; i < iters; ++i) {
                int leN = le + 2;
                float2 xB = make_float2(0.f, 0.f);
                if (leN < ne) {
                    int sN = __shfl(srcv, leN, 64);
                    xB = xin[(size_t)sN * CINC + c];
                }
                if (le < ne) {
                    const float4* sp = myst + le*9;
                    #pragma unroll
                    for (int j = 0; j < 9; ++j) {
                        float4 s = sp[j];
                        acc[2*j].x   = fmaf(s.x, xA.x, fmaf(-s.y, xA.y, acc[2*j].x));
                        acc[2*j].y   = fmaf(s.x, xA.y, fmaf( s.y, xA.x, acc[2*j].y));
                        acc[2*j+1].x = fmaf(s.z, xA.x, fmaf(-s.w, xA.y, acc[2*j+1].x));
                        acc[2*j+1].y = fmaf(s.z, xA.y, fmaf( s.w, xA.x, acc[2*j+1].y));
                    }
                }
                xA = xB; le = leN;
            }
        }
        // merge the two halves (half1 -> half0)
        #pragma unroll
        for (int k = 0; k < RM; ++k) {
            acc[k].x += __shfl_down(acc[k].x, 32, 64);
            acc[k].y += __shfl_down(acc[k].y, 32, 64);
        }
        if (h == 0) {
            #pragma unroll
            for (int k = 0; k < RM; ++k)
                agg[g*KK + k*32 + c] = acc[k];
        }
    }
    __syncthreads();

    // ---- einsum: out[n,d] = sum_k agg[n,k] * Wc[k,d] ----
    int ch = t >> 4;                        // 16 chunks of 36 k's
    int dp = (t & 15) * 2;                  // d-pair base
    int kb = ch * 36;                       // even
    float2 p0[NPB], p1[NPB];
    #pragma unroll
    for (int j = 0; j < NPB; ++j) { p0[j] = make_float2(0.f,0.f); p1[j] = make_float2(0.f,0.f); }
    #pragma unroll 6
    for (int i = 0; i < 18; ++i) {
        int q = kb + 2*i;
        float4 w0 = *(const float4*)(Wc + (size_t)q * COUTC + dp);       // k=q
        float4 w1 = *(const float4*)(Wc + (size_t)(q+1) * COUTC + dp);   // k=q+1
        #pragma unroll
        for (int j = 0; j < NPB; ++j) {
            float4 a = *(const float4*)(agg + j*KK + q);  // k=q (x,y), q+1 (z,w)
            p0[j].x += a.x*w0.x - a.y*w0.y;
            p0[j].y += a.x*w0.y + a.y*w0.x;
            p1[j].x += a.x*w0.z - a.y*w0.w;
            p1[j].y += a.x*w0.w + a.y*w0.z;
            p0[j].x += a.z*w1.x - a.w*w1.y;
            p0[j].y += a.z*w1.y + a.w*w1.x;
            p1[j].x += a.z*w1.z - a.w*w1.w;
            p1[j].y += a.z*w1.w + a.w*w1.z;
        }
    }
    __syncthreads();                        // all agg reads done; reuse as part
    float2* part = smem;                    // [16][PART_STRIDE] : [ch][j*32+d]
    #pragma unroll
    for (int j = 0; j < NPB; ++j)
        *(float4*)&part[(size_t)ch*PART_STRIDE + j*32 + dp] =
            make_float4(p0[j].x, p0[j].y, p1[j].x, p1[j].y);
    __syncthreads();

    // ---- reduce chunks, residual, nonlinearity ----
    if (t < NPB*32) {
        int j = t >> 5, d = t & 31;
        int n = nid[j];
        float2 hv = make_float2(0.f, 0.f);
        #pragma unroll
        for (int c2 = 0; c2 < 16; ++c2) {
            float2 vv = part[(size_t)c2*PART_STRIDE + j*32 + d];
            hv.x += vv.x; hv.y += vv.y;
        }
        if (FINAL) {
            const float2* xr = xres + (size_t)n * CINC;
            #pragma unroll
            for (int c = 0; c < CINC; ++c) {
                float2 xv = xr[c];
                float2 w = resw[c*COUTC + d];
                hv.x += xv.x*w.x - xv.y*w.y;
                hv.y += xv.x*w.y + xv.y*w.x;
            }
        }
        float mag = sqrtf(hv.x*hv.x + hv.y*hv.y);
        float num = mag + bias[d]; if (num < 0.f) num = 0.f;
        float den = (mag > EPSV) ? mag : EPSV;
        float f = num / den;
        out[(size_t)n*COUTC + d] = make_float2(f*hv.x, f*hv.y);
    }
}

// ---------------- launch ----------------

extern "C" void kernel_launch(void* const* d_in, const int* in_sizes, int n_in,
                              void* d_out, int out_size, void* d_ws, size_t ws_size,
                              hipStream_t stream) {
    const float2* xc   = (const float2*)d_in[0];   // (N,32,2) -> complex
    const int*   edges = (const int*)  d_in[1];    // (E,2)
    const float4* stenc4 = (const float4*)d_in[2]; // (E,6,3,2) -> (E,9) float4
    const float* w1    = (const float*)d_in[3];
    const float* off1  = (const float*)d_in[4];
    const float* b1    = (const float*)d_in[5];
    const float* w2    = (const float*)d_in[6];
    const float* off2  = (const float*)d_in[7];
    const float* b2    = (const float*)d_in[8];
    const float2* resw = (const float2*)d_in[9];   // (32,32) complex
    float2* out = (float2*)d_out;

    char* ws = (char*)d_ws;
    size_t o = 0;
    auto alloc = [&](size_t bytes) {
        o = (o + 255) & ~(size_t)255;
        size_t r = o; o += bytes; return r;
    };
    int*    cursor = (int*)   (ws + alloc(NN*sizeof(int)));
    int*    order  = (int*)   (ws + alloc(NN*sizeof(int)));
    int*    srcs   = (int*)   (ws + alloc((size_t)NN*CAP*sizeof(int)));
    int*    eids   = (int*)   (ws + alloc((size_t)NN*CAP*sizeof(int)));
    float2* Wc1    = (float2*)(ws + alloc((size_t)KK*COUTC*sizeof(float2)));
    float2* Wc2    = (float2*)(ws + alloc((size_t)KK*COUTC*sizeof(float2)));
    float2* h      = (float2*)(ws + alloc((size_t)NN*COUTC*sizeof(float2)));
    (void)ws_size; (void)in_sizes; (void)n_in; (void)out_size;

    hipMemsetAsync(cursor, 0, NN*sizeof(int), stream);
    k_build<<<(EE+255)/256, 256, 0, stream>>>(edges, cursor, w1, off1, w2, off2,
                                              Wc1, Wc2, srcs, eids);
    k_order<<<1, 1024, 0, stream>>>(cursor, order);

    k_conv<false><<<NN/NPB, 256, 0, stream>>>(xc, cursor, order, srcs, eids, stenc4,
                                              Wc1, b1, nullptr, nullptr, h);
    k_conv<true> <<<NN/NPB, 256, 0, stream>>>(h, cursor, order, srcs, eids, stenc4,
                                              Wc2, b2, xc, resw, out);
}

// Round 10
// 194.313 us; speedup vs baseline: 1.1873x; 1.1873x over previous
//
#include <hip/hip_runtime.h>

#define NN   10000
#define EE   160000
#define CINC 32
#define COUTC 32
#define RRR  6
#define MMM  3
#define RM   (RRR*MMM)      // 18
#define KK   (RM*CINC)      // 576
#define NPB  8              // nodes per block (one wave each)
#define CE   8              // edges staged per node per chunk
#define CAP  64             // fixed bucket capacity per node (mean degree 16)
#define AROW 592            // agg row stride in bf16 elems (576 + 16 pad)
#define EPSV 1e-8f

typedef __attribute__((ext_vector_type(8))) short bf16x8;
typedef __attribute__((ext_vector_type(4))) float f32x4;

__device__ inline short f2bf(float f) {            // round-to-nearest-even
    unsigned u = __float_as_uint(f);
    u = (u + 0x7FFF + ((u >> 16) & 1)) >> 16;
    return (short)u;
}

// ---------------- build: bf16 weight planes + direct bucket scatter ----------------
// cursor[] pre-zeroed by hipMemsetAsync. Wcb layout per conv: [re|im][d][k],
// k = rm*32+c — B-fragment-friendly (8 consecutive k per lane = 16B load).

__global__ void __launch_bounds__(256)
k_build(const int* __restrict__ edges, int* __restrict__ cursor,
        const float* __restrict__ w1, const float* __restrict__ off1,
        const float* __restrict__ w2, const float* __restrict__ off2,
        short* __restrict__ Wcb1, short* __restrict__ Wcb2,
        int* __restrict__ srcs, int* __restrict__ eids)
{
    int i = blockIdx.x*blockDim.x + threadIdx.x;
    if (i < KK*COUTC) {
        int d = i & 31;
        int k = i >> 5;                 // rm*32 + c
        int c = k & 31;
        float o1 = off1[c*COUTC + d];
        float o2 = off2[c*COUTC + d];
        float s1 = sinf(o1), c1 = cosf(o1);
        float s2 = sinf(o2), c2 = cosf(o2);
        Wcb1[d*KK + k]          = f2bf(w1[i]*c1);
        Wcb1[KK*COUTC + d*KK+k] = f2bf(w1[i]*s1);
        Wcb2[d*KK + k]          = f2bf(w2[i]*c2);
        Wcb2[KK*COUTC + d*KK+k] = f2bf(w2[i]*s2);
    }
    if (i < EE) {
        int src = edges[2*i];
        int tgt = edges[2*i+1];
        int pos = atomicAdd(&cursor[tgt], 1);
        if (pos < CAP) {
            srcs[tgt*CAP + pos] = src;
            eids[tgt*CAP + pos] = i;
        }
    }
}

// ---------------- degree counting-sort (single block) ----------------

__global__ void __launch_bounds__(1024)
k_order(const int* __restrict__ cnts, int* __restrict__ order) {
    __shared__ int bins[CAP+1];
    __shared__ int base[CAP+1];
    int t = threadIdx.x;
    if (t <= CAP) bins[t] = 0;
    __syncthreads();
    for (int n = t; n < NN; n += 1024) {
        int d = cnts[n]; if (d > CAP) d = CAP;
        atomicAdd(&bins[d], 1);
    }
    __syncthreads();
    if (t == 0) {
        int run = 0;
        #pragma unroll
        for (int b = 0; b <= CAP; ++b) { base[b] = run; run += bins[b]; }
    }
    __syncthreads();
    for (int n = t; n < NN; n += 1024) {
        int d = cnts[n]; if (d > CAP) d = CAP;
        int r = atomicAdd(&base[d], 1);
        order[r] = n;
    }
}

// ---------------- fused conv: fp32 edge phase + bf16 MFMA einsum ----------------
// 8 nodes/block, 512 threads = 8 waves, 1 node/wave. Edge phase as r9
// (LDS-staged stencil chunks, fp32 accumulate), then agg stored split-complex
// bf16 [re|im][8][AROW]. Einsum D[8m][32d] = agg x Wc via
// mfma_f32_16x16x32_bf16: rm-split over 8 waves (waves 0-1: 3 rm, 2-7: 2 rm),
// 4 product accs (rr,ii,ri,ir) x 2 N-tiles; A-frag from LDS (16B), B-frag from
// global bf16 planes (L2-resident). Cross-wave reduce via LDS dump (aliases
// agg), epilogue (residual + tangent nonlin) on threads 0-255.

template<bool FINAL>
__global__ void __launch_bounds__(512)
k_conv(const float2* __restrict__ xin,      // (NN,32) complex input
       const int*  __restrict__ cnts,       // (NN) per-node edge count
       const int*  __restrict__ order,      // (NN) degree-sorted node ids
       const int*  __restrict__ srcs,       // (NN*CAP) src node buckets
       const int*  __restrict__ eids,       // (NN*CAP) edge id buckets
       const float4* __restrict__ stenc4,   // (EE,9) float4 = (EE,18) complex
       const short* __restrict__ Wcb,       // [re|im][32][576] bf16
       const float* __restrict__ bias,      // (32)
       const float2* __restrict__ xres,     // (NN,32) original xc (FINAL)
       const float2* __restrict__ resw,     // (32,32) complex (FINAL)
       float2* __restrict__ out)            // (NN,32) complex
{
    __shared__ __align__(16) short aggS[2*NPB*AROW];   // 18944 B; later dump
    __shared__ __align__(16) float4 sten[NPB*CE*9];    // 9216 B stencil stage
    __shared__ int nid[NPB];
    int t = threadIdx.x;
    int g = t >> 6;                     // wave = node slot 0..7
    int l = t & 63;

    if (t < NPB) nid[t] = order[blockIdx.x*NPB + t];
    __syncthreads();

    // ---- edge aggregation (fp32) ----
    {
        int n = nid[g];
        int c = l & 31;
        int h = l >> 5;                 // half: alternate edges
        float4* myst = sten + g*(CE*9);
        float2 acc[RM];
        #pragma unroll
        for (int k = 0; k < RM; ++k) acc[k] = make_float2(0.f, 0.f);

        int beg = n*CAP;
        int cnt = cnts[n]; if (cnt > CAP) cnt = CAP;
        int end = beg + cnt;
        for (int eb = beg; eb < end; eb += CE) {
            int ne = end - eb; if (ne > CE) ne = CE;
            int nf4 = ne * 9;
            for (int idx = l; idx < nf4; idx += 64) {
                int e = idx / 9;
                int comp = idx - e*9;
                int eid = eids[eb + e];
                myst[idx] = stenc4[(size_t)eid*9 + comp];
            }
            int srcv = 0;
            if (l < ne) srcv = srcs[eb + l];

            int le = h;
            float2 xA = make_float2(0.f, 0.f);
            if (le < ne) {
                int s0 = __shfl(srcv, le, 64);
                xA = xin[(size_t)s0 * CINC + c];
            }
            int iters = (ne + 1) >> 1;
            for (int i = 0; i < iters; ++i) {
                int leN = le + 2;
                float2 xB = make_float2(0.f, 0.f);
                if (leN < ne) {
                    int sN = __shfl(srcv, leN, 64);
                    xB = xin[(size_t)sN * CINC + c];
                }
                if (le < ne) {
                    const float4* sp = myst + le*9;
                    #pragma unroll
                    for (int j = 0; j < 9; ++j) {
                        float4 s = sp[j];
                        acc[2*j].x   = fmaf(s.x, xA.x, fmaf(-s.y, xA.y, acc[2*j].x));
                        acc[2*j].y   = fmaf(s.x, xA.y, fmaf( s.y, xA.x, acc[2*j].y));
                        acc[2*j+1].x = fmaf(s.z, xA.x, fmaf(-s.w, xA.y, acc[2*j+1].x));
                        acc[2*j+1].y = fmaf(s.z, xA.y, fmaf( s.w, xA.x, acc[2*j+1].y));
                    }
                }
                xA = xB; le = leN;
            }
        }
        #pragma unroll
        for (int k = 0; k < RM; ++k) {
            acc[k].x += __shfl_down(acc[k].x, 32, 64);
            acc[k].y += __shfl_down(acc[k].y, 32, 64);
        }
        if (h == 0) {                   // write bf16 agg rows (always: deg==0 -> zeros)
            #pragma unroll
            for (int k = 0; k < RM; ++k) {
                aggS[g*AROW + k*32 + c]            = f2bf(acc[k].x);
                aggS[NPB*AROW + g*AROW + k*32 + c] = f2bf(acc[k].y);
            }
        }
    }
    __syncthreads();

    // ---- einsum via MFMA: D[m][d] = sum_k agg[m][k] * Wc[k][d] ----
    int quad = l >> 4;
    int nn16 = l & 15;
    int mrow = (nn16 < NPB) ? nn16 : NPB-1;       // rows >=8 ignored (dup of 7)
    int rm0 = (g < 2) ? 3*g : 2*g + 2;            // waves 0-1: 3 rm, else 2 rm
    int nrm = (g < 2) ? 3 : 2;
    const short* aggR = aggS;
    const short* aggI = aggS + NPB*AROW;
    const short* Wr = Wcb;
    const short* Wi = Wcb + KK*COUTC;

    f32x4 Prr[2], Pii[2], Pri[2], Pir[2];
    #pragma unroll
    for (int nt = 0; nt < 2; ++nt) {
        Prr[nt] = (f32x4)(0.f); Pii[nt] = (f32x4)(0.f);
        Pri[nt] = (f32x4)(0.f); Pir[nt] = (f32x4)(0.f);
    }
    for (int r = rm0; r < rm0 + nrm; ++r) {
        int koff = r*32 + quad*8;
        bf16x8 ar = *(const bf16x8*)(aggR + mrow*AROW + koff);
        bf16x8 ai = *(const bf16x8*)(aggI + mrow*AROW + koff);
        #pragma unroll
        for (int nt = 0; nt < 2; ++nt) {
            int d = nt*16 + nn16;
            bf16x8 br = *(const bf16x8*)(Wr + d*KK + koff);
            bf16x8 bi = *(const bf16x8*)(Wi + d*KK + koff);
            Prr[nt] = __builtin_amdgcn_mfma_f32_16x16x32_bf16(ar, br, Prr[nt], 0, 0, 0);
            Pii[nt] = __builtin_amdgcn_mfma_f32_16x16x32_bf16(ai, bi, Pii[nt], 0, 0, 0);
            Pri[nt] = __builtin_amdgcn_mfma_f32_16x16x32_bf16(ar, bi, Pri[nt], 0, 0, 0);
            Pir[nt] = __builtin_amdgcn_mfma_f32_16x16x32_bf16(ai, br, Pir[nt], 0, 0, 0);
        }
    }
    __syncthreads();                    // all agg reads done; reuse as dump

    // ---- dump partials: [wave][m][d] float2, rows m<8 only (quads 0,1) ----
    float2* dump = (float2*)aggS;       // 8*8*32*8 = 16384 B <= 18944
    if (quad < 2) {
        #pragma unroll
        for (int reg = 0; reg < 4; ++reg) {
            int m = quad*4 + reg;
            #pragma unroll
            for (int nt = 0; nt < 2; ++nt) {
                int d = nt*16 + nn16;
                dump[((size_t)g*NPB + m)*COUTC + d] =
                    make_float2(Prr[nt][reg] - Pii[nt][reg],
                                Pri[nt][reg] + Pir[nt][reg]);
            }
        }
    }
    __syncthreads();

    // ---- reduce 8 waves, residual, nonlinearity ----
    if (t < NPB*COUTC) {
        int m = t >> 5, d = t & 31;
        int n = nid[m];
        float2 hv = make_float2(0.f, 0.f);
        #pragma unroll
        for (int w = 0; w < NPB; ++w) {
            float2 v = dump[((size_t)w*NPB + m)*COUTC + d];
            hv.x += v.x; hv.y += v.y;
        }
        if (FINAL) {
            const float2* xr = xres + (size_t)n * CINC;
            #pragma unroll
            for (int c = 0; c < CINC; ++c) {
                float2 xv = xr[c];
                float2 w = resw[c*COUTC + d];
                hv.x += xv.x*w.x - xv.y*w.y;
                hv.y += xv.x*w.y + xv.y*w.x;
            }
        }
        float mag = sqrtf(hv.x*hv.x + hv.y*hv.y);
        float num = mag + bias[d]; if (num < 0.f) num = 0.f;
        float den = (mag > EPSV) ? mag : EPSV;
        float f = num / den;
        out[(size_t)n*COUTC + d] = make_float2(f*hv.x, f*hv.y);
    }
}

// ---------------- launch ----------------

extern "C" void kernel_launch(void* const* d_in, const int* in_sizes, int n_in,
                              void* d_out, int out_size, void* d_ws, size_t ws_size,
                              hipStream_t stream) {
    const float2* xc   = (const float2*)d_in[0];   // (N,32,2) -> complex
    const int*   edges = (const int*)  d_in[1];    // (E,2)
    const float4* stenc4 = (const float4*)d_in[2]; // (E,6,3,2) -> (E,9) float4
    const float* w1    = (const float*)d_in[3];
    const float* off1  = (const float*)d_in[4];
    const float* b1    = (const float*)d_in[5];
    const float* w2    = (const float*)d_in[6];
    const float* off2  = (const float*)d_in[7];
    const float* b2    = (const float*)d_in[8];
    const float2* resw = (const float2*)d_in[9];   // (32,32) complex
    float2* out = (float2*)d_out;

    char* ws = (char*)d_ws;
    size_t o = 0;
    auto alloc = [&](size_t bytes) {
        o = (o + 255) & ~(size_t)255;
        size_t r = o; o += bytes; return r;
    };
    int*    cursor = (int*)  (ws + alloc(NN*sizeof(int)));
    int*    order  = (int*)  (ws + alloc(NN*sizeof(int)));
    int*    srcs   = (int*)  (ws + alloc((size_t)NN*CAP*sizeof(int)));
    int*    eids   = (int*)  (ws + alloc((size_t)NN*CAP*sizeof(int)));
    short*  Wcb1   = (short*)(ws + alloc((size_t)2*KK*COUTC*sizeof(short)));
    short*  Wcb2   = (short*)(ws + alloc((size_t)2*KK*COUTC*sizeof(short)));
    float2* h      = (float2*)(ws + alloc((size_t)NN*COUTC*sizeof(float2)));
    (void)ws_size; (void)in_sizes; (void)n_in; (void)out_size;

    hipMemsetAsync(cursor, 0, NN*sizeof(int), stream);
    k_build<<<(EE+255)/256, 256, 0, stream>>>(edges, cursor, w1, off1, w2, off2,
                                              Wcb1, Wcb2, srcs, eids);
    k_order<<<1, 1024, 0, stream>>>(cursor, order);

    k_conv<false><<<NN/NPB, 512, 0, stream>>>(xc, cursor, order, srcs, eids, stenc4,
                                              Wcb1, b1, nullptr, nullptr, h);
    k_conv<true> <<<NN/NPB, 512, 0, stream>>>(h, cursor, order, srcs, eids, stenc4,
                                              Wcb2, b2, xc, resw, out);
}

// Round 12
// 180.128 us; speedup vs baseline: 1.2808x; 1.0788x over previous
//
#include <hip/hip_runtime.h>

#define NN   10000
#define EE   160000
#define CINC 32
#define COUTC 32
#define RRR  6
#define MMM  3
#define RM   (RRR*MMM)      // 18
#define KK   (RM*CINC)      // 576
#define NPB  8              // nodes per block (one wave each)
#define CE   8              // edges staged per node per chunk
#define CAP  64             // fixed bucket capacity per node (mean degree 16)
#define AROW 592            // agg row stride in bf16 elems (576 + 16 pad)
#define EPSV 1e-8f

typedef __attribute__((ext_vector_type(8))) short bf16x8;
typedef __attribute__((ext_vector_type(4))) float f32x4;

__device__ inline short f2bf(float f) {            // round-to-nearest-even
    unsigned u = __float_as_uint(f);
    u = (u + 0x7FFF + ((u >> 16) & 1)) >> 16;
    return (short)u;
}

// ---------------- build: bf16 weight planes + direct bucket scatter ----------------

__global__ void __launch_bounds__(256)
k_build(const int* __restrict__ edges, int* __restrict__ cursor,
        const float* __restrict__ w1, const float* __restrict__ off1,
        const float* __restrict__ w2, const float* __restrict__ off2,
        short* __restrict__ Wcb1, short* __restrict__ Wcb2,
        int* __restrict__ srcs, int* __restrict__ eids)
{
    int i = blockIdx.x*blockDim.x + threadIdx.x;
    if (i < KK*COUTC) {
        int d = i & 31;
        int k = i >> 5;                 // rm*32 + c
        int c = k & 31;
        float o1 = off1[c*COUTC + d];
        float o2 = off2[c*COUTC + d];
        float s1 = sinf(o1), c1 = cosf(o1);
        float s2 = sinf(o2), c2 = cosf(o2);
        Wcb1[d*KK + k]          = f2bf(w1[i]*c1);
        Wcb1[KK*COUTC + d*KK+k] = f2bf(w1[i]*s1);
        Wcb2[d*KK + k]          = f2bf(w2[i]*c2);
        Wcb2[KK*COUTC + d*KK+k] = f2bf(w2[i]*s2);
    }
    if (i < EE) {
        int src = edges[2*i];
        int tgt = edges[2*i+1];
        int pos = atomicAdd(&cursor[tgt], 1);
        if (pos < CAP) {
            srcs[tgt*CAP + pos] = src;
            eids[tgt*CAP + pos] = i;
        }
    }
}

// ---------------- degree counting-sort (single block) ----------------

__global__ void __launch_bounds__(1024)
k_order(const int* __restrict__ cnts, int* __restrict__ order) {
    __shared__ int bins[CAP+1];
    __shared__ int base[CAP+1];
    int t = threadIdx.x;
    if (t <= CAP) bins[t] = 0;
    __syncthreads();
    for (int n = t; n < NN; n += 1024) {
        int d = cnts[n]; if (d > CAP) d = CAP;
        atomicAdd(&bins[d], 1);
    }
    __syncthreads();
    if (t == 0) {
        int run = 0;
        #pragma unroll
        for (int b = 0; b <= CAP; ++b) { base[b] = run; run += bins[b]; }
    }
    __syncthreads();
    for (int n = t; n < NN; n += 1024) {
        int d = cnts[n]; if (d > CAP) d = CAP;
        int r = atomicAdd(&base[d], 1);
        order[r] = n;
    }
}

// ---------------- fused conv: pipelined fp32 edge phase + bf16 MFMA einsum ----------------
// 8 nodes/block, 512 threads = 8 waves, 1 node/wave. Per-node srcs/eids in
// registers (lane l = slot l). Chunk loop software-pipelined: issue chunk
// k+1's global loads -> compute chunk k from LDS (double-buffered) ->
// ds_write chunk k+1. ALL __shfl broadcasts execute unconditionally with the
// full wave (ds_bpermute reads garbage from EXEC-inactive source lanes —
// that was r11's correctness bug); only the dependent global loads are
// predicated. Einsum via mfma_f32_16x16x32_bf16 (r10 layout).

template<bool FINAL>
__global__ void __launch_bounds__(512)
k_conv(const float2* __restrict__ xin,      // (NN,32) complex input
       const int*  __restrict__ cnts,       // (NN) per-node edge count
       const int*  __restrict__ order,      // (NN) degree-sorted node ids
       const int*  __restrict__ srcs,       // (NN*CAP) src node buckets
       const int*  __restrict__ eids,       // (NN*CAP) edge id buckets
       const float4* __restrict__ stenc4,   // (EE,9) float4 = (EE,18) complex
       const short* __restrict__ Wcb,       // [re|im][32][576] bf16
       const float* __restrict__ bias,      // (32)
       const float2* __restrict__ xres,     // (NN,32) original xc (FINAL)
       const float2* __restrict__ resw,     // (32,32) complex (FINAL)
       float2* __restrict__ out)            // (NN,32) complex
{
    __shared__ __align__(16) short aggS[2*NPB*AROW];     // 18944 B; later dump
    __shared__ __align__(16) float4 sten[NPB*2*CE*9];    // 18432 B dbuf stage
    __shared__ int nid[NPB];
    int t = threadIdx.x;
    int g = t >> 6;                     // wave = node slot 0..7
    int l = t & 63;

    if (t < NPB) nid[t] = order[blockIdx.x*NPB + t];
    __syncthreads();

    // ---- edge aggregation (fp32, pipelined) ----
    {
        int n = nid[g];
        int c = l & 31;
        int h = l >> 5;                 // half: alternate edges
        int cnt = cnts[n]; if (cnt > CAP) cnt = CAP;
        int beg = n*CAP;
        int srcAll = 0, eidAll = 0;
        if (l < cnt) { srcAll = srcs[beg + l]; eidAll = eids[beg + l]; }

        // staging slot assignment (loop-invariant): lane covers idx l and l+64
        int e0 = l/9,      cp0 = l - 9*e0;
        int e1 = (l+64)/9, cp1 = (l+64) - 9*e1;

        float4* bufA = sten + g*(2*CE*9);
        float4* bufB = bufA + CE*9;

        float2 acc[RM];
        #pragma unroll
        for (int k = 0; k < RM; ++k) acc[k] = make_float2(0.f, 0.f);

        int nchunks = (cnt + CE - 1) / CE;
        float4 r0 = make_float4(0,0,0,0), r1 = r0;
        float2 xq[CE/2], xn[CE/2];

        auto stage_load = [&](int ck) {
            int ne = cnt - ck*CE; if (ne > CE) ne = CE;
            int nf4 = ne*9;
            // shfl UNCONDITIONAL (full wave active -> all source lanes valid)
            int s0i = ck*CE + e0; if (s0i > 63) s0i = 63;
            int s1i = ck*CE + e1; if (s1i > 63) s1i = 63;
            int eidA = __shfl(eidAll, s0i, 64);
            int eidB = __shfl(eidAll, s1i, 64);
            r0 = make_float4(0,0,0,0); r1 = r0;
            if (l < nf4)      r0 = stenc4[(size_t)eidA*9 + cp0];
            if (l + 64 < nf4) r1 = stenc4[(size_t)eidB*9 + cp1];
        };
        auto load_x = [&](int ck, float2* xr) {
            int ne = cnt - ck*CE; if (ne > CE) ne = CE;
            #pragma unroll
            for (int i = 0; i < CE/2; ++i) {
                int le = h + 2*i;
                int sl = ck*CE + le; if (sl > 63) sl = 63;
                int s = __shfl(srcAll, sl, 64);      // unconditional
                float2 v = make_float2(0.f, 0.f);
                if (le < ne) v = xin[(size_t)s*CINC + c];
                xr[i] = v;
            }
        };
        auto stage_write = [&](float4* dst, int ck) {
            int ne = cnt - ck*CE; if (ne > CE) ne = CE;
            int nf4 = ne*9;
            if (l < nf4)      dst[l] = r0;
            if (l + 64 < nf4) dst[l+64] = r1;
        };

        if (nchunks > 0) {
            stage_load(0); load_x(0, xq); stage_write(bufA, 0);
            for (int ck = 0; ck < nchunks; ++ck) {
                float4* cur = (ck & 1) ? bufB : bufA;
                float4* nxt = (ck & 1) ? bufA : bufB;
                bool more = (ck + 1 < nchunks);
                if (more) { stage_load(ck+1); load_x(ck+1, xn); }
                int ne = cnt - ck*CE; if (ne > CE) ne = CE;
                #pragma unroll
                for (int i = 0; i < CE/2; ++i) {
                    int le = h + 2*i;
                    if (le < ne) {
                        const float4* sp = cur + le*9;
                        float2 xv = xq[i];
                        #pragma unroll
                        for (int j = 0; j < 9; ++j) {
                            float4 s = sp[j];
                            acc[2*j].x   = fmaf(s.x, xv.x, fmaf(-s.y, xv.y, acc[2*j].x));
                            acc[2*j].y   = fmaf(s.x, xv.y, fmaf( s.y, xv.x, acc[2*j].y));
                            acc[2*j+1].x = fmaf(s.z, xv.x, fmaf(-s.w, xv.y, acc[2*j+1].x));
                            acc[2*j+1].y = fmaf(s.z, xv.y, fmaf( s.w, xv.x, acc[2*j+1].y));
                        }
                    }
                }
                if (more) {
                    stage_write(nxt, ck+1);
                    #pragma unroll
                    for (int i = 0; i < CE/2; ++i) xq[i] = xn[i];
                }
            }
        }

        #pragma unroll
        for (int k = 0; k < RM; ++k) {
            acc[k].x += __shfl_down(acc[k].x, 32, 64);
            acc[k].y += __shfl_down(acc[k].y, 32, 64);
        }
        if (h == 0) {                   // bf16 agg rows (deg==0 -> zeros)
            #pragma unroll
            for (int k = 0; k < RM; ++k) {
                aggS[g*AROW + k*32 + c]            = f2bf(acc[k].x);
                aggS[NPB*AROW + g*AROW + k*32 + c] = f2bf(acc[k].y);
            }
        }
    }
    __syncthreads();

    // ---- einsum via MFMA: D[m][d] = sum_k agg[m][k] * Wc[k][d] ----
    int quad = l >> 4;
    int nn16 = l & 15;
    int mrow = (nn16 < NPB) ? nn16 : NPB-1;       // rows >=8 ignored (dup of 7)
    int rm0 = (g < 2) ? 3*g : 2*g + 2;            // waves 0-1: 3 rm, else 2 rm
    int nrm = (g < 2) ? 3 : 2;
    const short* aggR = aggS;
    const short* aggI = aggS + NPB*AROW;
    const short* Wr = Wcb;
    const short* Wi = Wcb + KK*COUTC;

    f32x4 Prr[2], Pii[2], Pri[2], Pir[2];
    #pragma unroll
    for (int nt = 0; nt < 2; ++nt) {
        Prr[nt] = (f32x4)(0.f); Pii[nt] = (f32x4)(0.f);
        Pri[nt] = (f32x4)(0.f); Pir[nt] = (f32x4)(0.f);
    }
    for (int r = rm0; r < rm0 + nrm; ++r) {
        int koff = r*32 + quad*8;
        bf16x8 ar = *(const bf16x8*)(aggR + mrow*AROW + koff);
        bf16x8 ai = *(const bf16x8*)(aggI + mrow*AROW + koff);
        #pragma unroll
        for (int nt = 0; nt < 2; ++nt) {
            int d = nt*16 + nn16;
            bf16x8 br = *(const bf16x8*)(Wr + d*KK + koff);
            bf16x8 bi = *(const bf16x8*)(Wi + d*KK + koff);
            Prr[nt] = __builtin_amdgcn_mfma_f32_16x16x32_bf16(ar, br, Prr[nt], 0, 0, 0);
            Pii[nt] = __builtin_amdgcn_mfma_f32_16x16x32_bf16(ai, bi, Pii[nt], 0, 0, 0);
            Pri[nt] = __builtin_amdgcn_mfma_f32_16x16x32_bf16(ar, bi, Pri[nt], 0, 0, 0);
            Pir[nt] = __builtin_amdgcn_mfma_f32_16x16x32_bf16(ai, br, Pir[nt], 0, 0, 0);
        }
    }
    __syncthreads();                    // all agg reads done; reuse as dump

    // ---- dump partials: [wave][m][d] float2, rows m<8 only (quads 0,1) ----
    float2* dump = (float2*)aggS;       // 16384 B <= 18944
    if (quad < 2) {
        #pragma unroll
        for (int reg = 0; reg < 4; ++reg) {
            int m = quad*4 + reg;
            #pragma unroll
            for (int nt = 0; nt < 2; ++nt) {
                int d = nt*16 + nn16;
                dump[((size_t)g*NPB + m)*COUTC + d] =
                    make_float2(Prr[nt][reg] - Pii[nt][reg],
                                Pri[nt][reg] + Pir[nt][reg]);
            }
        }
    }
    __syncthreads();

    // ---- reduce 8 waves, residual, nonlinearity ----
    if (t < NPB*COUTC) {
        int m = t >> 5, d = t & 31;
        int n = nid[m];
        float2 hv = make_float2(0.f, 0.f);
        #pragma unroll
        for (int w = 0; w < NPB; ++w) {
            float2 v = dump[((size_t)w*NPB + m)*COUTC + d];
            hv.x += v.x; hv.y += v.y;
        }
        if (FINAL) {
            const float2* xr = xres + (size_t)n * CINC;
            #pragma unroll
            for (int c = 0; c < CINC; ++c) {
                float2 xv = xr[c];
                float2 w = resw[c*COUTC + d];
                hv.x += xv.x*w.x - xv.y*w.y;
                hv.y += xv.x*w.y + xv.y*w.x;
            }
        }
        float mag = sqrtf(hv.x*hv.x + hv.y*hv.y);
        float num = mag + bias[d]; if (num < 0.f) num = 0.f;
        float den = (mag > EPSV) ? mag : EPSV;
        float f = num / den;
        out[(size_t)n*COUTC + d] = make_float2(f*hv.x, f*hv.y);
    }
}

// ---------------- launch ----------------

extern "C" void kernel_launch(void* const* d_in, const int* in_sizes, int n_in,
                              void* d_out, int out_size, void* d_ws, size_t ws_size,
                              hipStream_t stream) {
    const float2* xc   = (const float2*)d_in[0];   // (N,32,2) -> complex
    const int*   edges = (const int*)  d_in[1];    // (E,2)
    const float4* stenc4 = (const float4*)d_in[2]; // (E,6,3,2) -> (E,9) float4
    const float* w1    = (const float*)d_in[3];
    const float* off1  = (const float*)d_in[4];
    const float* b1    = (const float*)d_in[5];
    const float* w2    = (const float*)d_in[6];
    const float* off2  = (const float*)d_in[7];
    const float* b2    = (const float*)d_in[8];
    const float2* resw = (const float2*)d_in[9];   // (32,32) complex
    float2* out = (float2*)d_out;

    char* ws = (char*)d_ws;
    size_t o = 0;
    auto alloc = [&](size_t bytes) {
        o = (o + 255) & ~(size_t)255;
        size_t r = o; o += bytes; return r;
    };
    int*    cursor = (int*)  (ws + alloc(NN*sizeof(int)));
    int*    order  = (int*)  (ws + alloc(NN*sizeof(int)));
    int*    srcs   = (int*)  (ws + alloc((size_t)NN*CAP*sizeof(int)));
    int*    eids   = (int*)  (ws + alloc((size_t)NN*CAP*sizeof(int)));
    short*  Wcb1   = (short*)(ws + alloc((size_t)2*KK*COUTC*sizeof(short)));
    short*  Wcb2   = (short*)(ws + alloc((size_t)2*KK*COUTC*sizeof(short)));
    float2* h      = (float2*)(ws + alloc((size_t)NN*COUTC*sizeof(float2)));
    (void)ws_size; (void)in_sizes; (void)n_in; (void)out_size;

    hipMemsetAsync(cursor, 0, NN*sizeof(int), stream);
    k_build<<<(EE+255)/256, 256, 0, stream>>>(edges, cursor, w1, off1, w2, off2,
                                              Wcb1, Wcb2, srcs, eids);
    k_order<<<1, 1024, 0, stream>>>(cursor, order);

    k_conv<false><<<NN/NPB, 512, 0, stream>>>(xc, cursor, order, srcs, eids, stenc4,
                                              Wcb1, b1, nullptr, nullptr, h);
    k_conv<true> <<<NN/NPB, 512, 0, stream>>>(h, cursor, order, srcs, eids, stenc4,
                                              Wcb2, b2, xc, resw, out);
}

// Round 13
// 176.569 us; speedup vs baseline: 1.3066x; 1.0202x over previous
//
#include <hip/hip_runtime.h>

#define NN   10000
#define EE   160000
#define CINC 32
#define COUTC 32
#define RRR  6
#define MMM  3
#define RM   (RRR*MMM)      // 18
#define KK   (RM*CINC)      // 576
#define NPB  8              // nodes per block (one wave each)
#define CE   8              // edges staged per node per chunk
#define CAP  64             // fixed bucket capacity per node (mean degree 16)
#define AROW 592            // agg row stride in bf16 elems (576 + 16 pad)
#define EPSV 1e-8f

typedef __attribute__((ext_vector_type(8))) short bf16x8;
typedef __attribute__((ext_vector_type(4))) float f32x4;

__device__ inline short f2bf(float f) {            // round-to-nearest-even
    unsigned u = __float_as_uint(f);
    u = (u + 0x7FFF + ((u >> 16) & 1)) >> 16;
    return (short)u;
}

// ---------------- build: bf16 weight planes + direct bucket scatter ----------------
// cursor[] pre-zeroed by hipMemsetAsync. Buckets hold (src,eid) as int2 --
// one 8B scattered store per edge instead of two 4B stores.

__global__ void __launch_bounds__(256)
k_build(const int* __restrict__ edges, int* __restrict__ cursor,
        const float* __restrict__ w1, const float* __restrict__ off1,
        const float* __restrict__ w2, const float* __restrict__ off2,
        short* __restrict__ Wcb1, short* __restrict__ Wcb2,
        int2* __restrict__ sei)
{
    int i = blockIdx.x*blockDim.x + threadIdx.x;
    if (i < KK*COUTC) {
        int d = i & 31;
        int k = i >> 5;                 // rm*32 + c
        int c = k & 31;
        float o1 = off1[c*COUTC + d];
        float o2 = off2[c*COUTC + d];
        float s1 = sinf(o1), c1 = cosf(o1);
        float s2 = sinf(o2), c2 = cosf(o2);
        Wcb1[d*KK + k]          = f2bf(w1[i]*c1);
        Wcb1[KK*COUTC + d*KK+k] = f2bf(w1[i]*s1);
        Wcb2[d*KK + k]          = f2bf(w2[i]*c2);
        Wcb2[KK*COUTC + d*KK+k] = f2bf(w2[i]*s2);
    }
    if (i < EE) {
        int src = edges[2*i];
        int tgt = edges[2*i+1];
        int pos = atomicAdd(&cursor[tgt], 1);
        if (pos < CAP) sei[tgt*CAP + pos] = make_int2(src, i);
    }
}

// ---------------- degree counting-sort, DESCENDING (single block) ----------------
// Longest blocks dispatch first -> no straggler tail (ascending order put all
// max-degree blocks at the end of the grid, serializing them on a near-empty
// machine).

__global__ void __launch_bounds__(1024)
k_order(const int* __restrict__ cnts, int* __restrict__ order) {
    __shared__ int bins[CAP+1];
    __shared__ int base[CAP+1];
    int t = threadIdx.x;
    if (t <= CAP) bins[t] = 0;
    __syncthreads();
    for (int n = t; n < NN; n += 1024) {
        int d = cnts[n]; if (d > CAP) d = CAP;
        atomicAdd(&bins[d], 1);
    }
    __syncthreads();
    if (t == 0) {
        int run = 0;
        for (int b = CAP; b >= 0; --b) { base[b] = run; run += bins[b]; }
    }
    __syncthreads();
    for (int n = t; n < NN; n += 1024) {
        int d = cnts[n]; if (d > CAP) d = CAP;
        int r = atomicAdd(&base[d], 1);
        order[r] = n;
    }
}

// ---------------- fused conv: pipelined fp32 edge phase + bf16 MFMA einsum ----------------
// 8 nodes/block, 512 threads = 8 waves, 1 node/wave. Per-node (src,eid) in
// registers (lane l = slot l, int2). Chunk loop software-pipelined: issue
// chunk k+1's global loads -> compute chunk k from LDS (double-buffered) ->
// ds_write chunk k+1. ALL __shfl broadcasts execute unconditionally with the
// full wave (ds_bpermute reads garbage from EXEC-inactive source lanes);
// only the dependent global loads are predicated. Einsum via
// mfma_f32_16x16x32_bf16 (r10 layout).

template<bool FINAL>
__global__ void __launch_bounds__(512)
k_conv(const float2* __restrict__ xin,      // (NN,32) complex input
       const int*  __restrict__ cnts,       // (NN) per-node edge count
       const int*  __restrict__ order,      // (NN) degree-sorted node ids (desc)
       const int2* __restrict__ sei,        // (NN*CAP) (src,eid) buckets
       const float4* __restrict__ stenc4,   // (EE,9) float4 = (EE,18) complex
       const short* __restrict__ Wcb,       // [re|im][32][576] bf16
       const float* __restrict__ bias,      // (32)
       const float2* __restrict__ xres,     // (NN,32) original xc (FINAL)
       const float2* __restrict__ resw,     // (32,32) complex (FINAL)
       float2* __restrict__ out)            // (NN,32) complex
{
    __shared__ __align__(16) short aggS[2*NPB*AROW];     // 18944 B; later dump
    __shared__ __align__(16) float4 sten[NPB*2*CE*9];    // 18432 B dbuf stage
    __shared__ int nid[NPB];
    int t = threadIdx.x;
    int g = t >> 6;                     // wave = node slot 0..7
    int l = t & 63;

    if (t < NPB) nid[t] = order[blockIdx.x*NPB + t];
    __syncthreads();

    // ---- edge aggregation (fp32, pipelined) ----
    {
        int n = nid[g];
        int c = l & 31;
        int h = l >> 5;                 // half: alternate edges
        int cnt = cnts[n]; if (cnt > CAP) cnt = CAP;
        int beg = n*CAP;
        int srcAll = 0, eidAll = 0;
        if (l < cnt) { int2 v = sei[beg + l]; srcAll = v.x; eidAll = v.y; }

        // staging slot assignment (loop-invariant): lane covers idx l and l+64
        int e0 = l/9,      cp0 = l - 9*e0;
        int e1 = (l+64)/9, cp1 = (l+64) - 9*e1;

        float4* bufA = sten + g*(2*CE*9);
        float4* bufB = bufA + CE*9;

        float2 acc[RM];
        #pragma unroll
        for (int k = 0; k < RM; ++k) acc[k] = make_float2(0.f, 0.f);

        int nchunks = (cnt + CE - 1) / CE;
        float4 r0 = make_float4(0,0,0,0), r1 = r0;
        float2 xq[CE/2], xn[CE/2];

        auto stage_load = [&](int ck) {
            int ne = cnt - ck*CE; if (ne > CE) ne = CE;
            int nf4 = ne*9;
            // shfl UNCONDITIONAL (full wave active -> all source lanes valid)
            int s0i = ck*CE + e0; if (s0i > 63) s0i = 63;
            int s1i = ck*CE + e1; if (s1i > 63) s1i = 63;
            int eidA = __shfl(eidAll, s0i, 64);
            int eidB = __shfl(eidAll, s1i, 64);
            r0 = make_float4(0,0,0,0); r1 = r0;
            if (l < nf4)      r0 = stenc4[(size_t)eidA*9 + cp0];
            if (l + 64 < nf4) r1 = stenc4[(size_t)eidB*9 + cp1];
        };
        auto load_x = [&](int ck, float2* xr) {
            int ne = cnt - ck*CE; if (ne > CE) ne = CE;
            #pragma unroll
            for (int i = 0; i < CE/2; ++i) {
                int le = h + 2*i;
                int sl = ck*CE + le; if (sl > 63) sl = 63;
                int s = __shfl(srcAll, sl, 64);      // unconditional
                float2 v = make_float2(0.f, 0.f);
                if (le < ne) v = xin[(size_t)s*CINC + c];
                xr[i] = v;
            }
        };
        auto stage_write = [&](float4* dst, int ck) {
            int ne = cnt - ck*CE; if (ne > CE) ne = CE;
            int nf4 = ne*9;
            if (l < nf4)      dst[l] = r0;
            if (l + 64 < nf4) dst[l+64] = r1;
        };

        if (nchunks > 0) {
            stage_load(0); load_x(0, xq); stage_write(bufA, 0);
            for (int ck = 0; ck < nchunks; ++ck) {
                float4* cur = (ck & 1) ? bufB : bufA;
                float4* nxt = (ck & 1) ? bufA : bufB;
                bool more = (ck + 1 < nchunks);
                if (more) { stage_load(ck+1); load_x(ck+1, xn); }
                int ne = cnt - ck*CE; if (ne > CE) ne = CE;
                #pragma unroll
                for (int i = 0; i < CE/2; ++i) {
                    int le = h + 2*i;
                    if (le < ne) {
                        const float4* sp = cur + le*9;
                        float2 xv = xq[i];
                        #pragma unroll
                        for (int j = 0; j < 9; ++j) {
                            float4 s = sp[j];
                            acc[2*j].x   = fmaf(s.x, xv.x, fmaf(-s.y, xv.y, acc[2*j].x));
                            acc[2*j].y   = fmaf(s.x, xv.y, fmaf( s.y, xv.x, acc[2*j].y));
                            acc[2*j+1].x = fmaf(s.z, xv.x, fmaf(-s.w, xv.y, acc[2*j+1].x));
                            acc[2*j+1].y = fmaf(s.z, xv.y, fmaf( s.w, xv.x, acc[2*j+1].y));
                        }
                    }
                }
                if (more) {
                    stage_write(nxt, ck+1);
                    #pragma unroll
                    for (int i = 0; i < CE/2; ++i) xq[i] = xn[i];
                }
            }
        }

        #pragma unroll
        for (int k = 0; k < RM; ++k) {
            acc[k].x += __shfl_down(acc[k].x, 32, 64);
            acc[k].y += __shfl_down(acc[k].y, 32, 64);
        }
        if (h == 0) {                   // bf16 agg rows (deg==0 -> zeros)
            #pragma unroll
            for (int k = 0; k < RM; ++k) {
                aggS[g*AROW + k*32 + c]            = f2bf(acc[k].x);
                aggS[NPB*AROW + g*AROW + k*32 + c] = f2bf(acc[k].y);
            }
        }
    }
    __syncthreads();

    // ---- einsum via MFMA: D[m][d] = sum_k agg[m][k] * Wc[k][d] ----
    int quad = l >> 4;
    int nn16 = l & 15;
    int mrow = (nn16 < NPB) ? nn16 : NPB-1;       // rows >=8 ignored (dup of 7)
    int rm0 = (g < 2) ? 3*g : 2*g + 2;            // waves 0-1: 3 rm, else 2 rm
    int nrm = (g < 2) ? 3 : 2;
    const short* aggR = aggS;
    const short* aggI = aggS + NPB*AROW;
    const short* Wr = Wcb;
    const short* Wi = Wcb + KK*COUTC;

    f32x4 Prr[2], Pii[2], Pri[2], Pir[2];
    #pragma unroll
    for (int nt = 0; nt < 2; ++nt) {
        Prr[nt] = (f32x4)(0.f); Pii[nt] = (f32x4)(0.f);
        Pri[nt] = (f32x4)(0.f); Pir[nt] = (f32x4)(0.f);
    }
    for (int r = rm0; r < rm0 + nrm; ++r) {
        int koff = r*32 + quad*8;
        bf16x8 ar = *(const bf16x8*)(aggR + mrow*AROW + koff);
        bf16x8 ai = *(const bf16x8*)(aggI + mrow*AROW + koff);
        #pragma unroll
        for (int nt = 0; nt < 2; ++nt) {
            int d = nt*16 + nn16;
            bf16x8 br = *(const bf16x8*)(Wr + d*KK + koff);
            bf16x8 bi = *(const bf16x8*)(Wi + d*KK + koff);
            Prr[nt] = __builtin_amdgcn_mfma_f32_16x16x32_bf16(ar, br, Prr[nt], 0, 0, 0);
            Pii[nt] = __builtin_amdgcn_mfma_f32_16x16x32_bf16(ai, bi, Pii[nt], 0, 0, 0);
            Pri[nt] = __builtin_amdgcn_mfma_f32_16x16x32_bf16(ar, bi, Pri[nt], 0, 0, 0);
            Pir[nt] = __builtin_amdgcn_mfma_f32_16x16x32_bf16(ai, br, Pir[nt], 0, 0, 0);
        }
    }
    __syncthreads();                    // all agg reads done; reuse as dump

    // ---- dump partials: [wave][m][d] float2, rows m<8 only (quads 0,1) ----
    float2* dump = (float2*)aggS;       // 16384 B <= 18944
    if (quad < 2) {
        #pragma unroll
        for (int reg = 0; reg < 4; ++reg) {
            int m = quad*4 + reg;
            #pragma unroll
            for (int nt = 0; nt < 2; ++nt) {
                int d = nt*16 + nn16;
                dump[((size_t)g*NPB + m)*COUTC + d] =
                    make_float2(Prr[nt][reg] - Pii[nt][reg],
                                Pri[nt][reg] + Pir[nt][reg]);
            }
        }
    }
    __syncthreads();

    // ---- reduce 8 waves, residual, nonlinearity ----
    if (t < NPB*COUTC) {
        int m = t >> 5, d = t & 31;
        int n = nid[m];
        float2 hv = make_float2(0.f, 0.f);
        #pragma unroll
        for (int w = 0; w < NPB; ++w) {
            float2 v = dump[((size_t)w*NPB + m)*COUTC + d];
            hv.x += v.x; hv.y += v.y;
        }
        if (FINAL) {
            const float2* xr = xres + (size_t)n * CINC;
            #pragma unroll
            for (int c = 0; c < CINC; ++c) {
                float2 xv = xr[c];
                float2 w = resw[c*COUTC + d];
                hv.x += xv.x*w.x - xv.y*w.y;
                hv.y += xv.x*w.y + xv.y*w.x;
            }
        }
        float mag = sqrtf(hv.x*hv.x + hv.y*hv.y);
        float num = mag + bias[d]; if (num < 0.f) num = 0.f;
        float den = (mag > EPSV) ? mag : EPSV;
        float f = num / den;
        out[(size_t)n*COUTC + d] = make_float2(f*hv.x, f*hv.y);
    }
}

// ---------------- launch ----------------

extern "C" void kernel_launch(void* const* d_in, const int* in_sizes, int n_in,
                              void* d_out, int out_size, void* d_ws, size_t ws_size,
                              hipStream_t stream) {
    const float2* xc   = (const float2*)d_in[0];   // (N,32,2) -> complex
    const int*   edges = (const int*)  d_in[1];    // (E,2)
    const float4* stenc4 = (const float4*)d_in[2]; // (E,6,3,2) -> (E,9) float4
    const float* w1    = (const float*)d_in[3];
    const float* off1  = (const float*)d_in[4];
    const float* b1    = (const float*)d_in[5];
    const float* w2    = (const float*)d_in[6];
    const float* off2  = (const float*)d_in[7];
    const float* b2    = (const float*)d_in[8];
    const float2* resw = (const float2*)d_in[9];   // (32,32) complex
    float2* out = (float2*)d_out;

    char* ws = (char*)d_ws;
    size_t o = 0;
    auto alloc = [&](size_t bytes) {
        o = (o + 255) & ~(size_t)255;
        size_t r = o; o += bytes; return r;
    };
    int*    cursor = (int*)  (ws + alloc(NN*sizeof(int)));
    int*    order  = (int*)  (ws + alloc(NN*sizeof(int)));
    int2*   sei    = (int2*) (ws + alloc((size_t)NN*CAP*sizeof(int2)));
    short*  Wcb1   = (short*)(ws + alloc((size_t)2*KK*COUTC*sizeof(short)));
    short*  Wcb2   = (short*)(ws + alloc((size_t)2*KK*COUTC*sizeof(short)));
    float2* h      = (float2*)(ws + alloc((size_t)NN*COUTC*sizeof(float2)));
    (void)ws_size; (void)in_sizes; (void)n_in; (void)out_size;

    hipMemsetAsync(cursor, 0, NN*sizeof(int), stream);
    k_build<<<(EE+255)/256, 256, 0, stream>>>(edges, cursor, w1, off1, w2, off2,
                                              Wcb1, Wcb2, sei);
    k_order<<<1, 1024, 0, stream>>>(cursor, order);

    k_conv<false><<<NN/NPB, 512, 0, stream>>>(xc, cursor, order, sei, stenc4,
                                              Wcb1, b1, nullptr, nullptr, h);
    k_conv<true> <<<NN/NPB, 512, 0, stream>>>(h, cursor, order, sei, stenc4,
                                              Wcb2, b2, xc, resw, out);
}